// Round 4
// baseline (377.354 us; speedup 1.0000x reference)
//
#include <hip/hip_runtime.h>
#include <hip/hip_bf16.h>

#define FDIM 64
#define N_PIXELS 65536
#define N_GENES 30000
#define WAVES_PER_BLOCK 4
#define BATCH 4   // pixels grabbed per atomic

// ---------- kernel A: f32 tokens -> bf16 table in ws (RNE) ----------
__device__ __forceinline__ unsigned short f32_to_bf16_rne(float f) {
    unsigned int u = __float_as_uint(f);
    u = (u + 0x7FFFu + ((u >> 16) & 1u)) >> 16;
    return (unsigned short)u;
}

__global__ __launch_bounds__(256) void convert_tokens(
    const float4* __restrict__ tokens4,   // 480000 float4
    ushort4* __restrict__ tok_bf)         // 480000 ushort4 (bf16)
{
    const int i = blockIdx.x * blockDim.x + threadIdx.x;   // exactly 480000
    const float4 t = tokens4[i];
    ushort4 o;
    o.x = f32_to_bf16_rne(t.x);
    o.y = f32_to_bf16_rne(t.y);
    o.z = f32_to_bf16_rne(t.z);
    o.w = f32_to_bf16_rne(t.w);
    tok_bf[i] = o;
}

// ---------- kernel B: main gather-scatter, dynamic pixel assignment ----------
__global__ __launch_bounds__(WAVES_PER_BLOCK * 64) void sgstem_main(
    const int* __restrict__ indices,
    const float* __restrict__ cnts,
    const int* __restrict__ indptr,
    const float* __restrict__ gamma,
    const uint4* __restrict__ tok_bf,     // (N_GENES, 8) uint4 rows, 128 B each
    float4* __restrict__ out4,            // (N_PIXELS, 16) float4
    unsigned int* __restrict__ counter)
{
    __shared__ int2 meta[WAVES_PER_BLOCK][64];   // {idx, scale_bits}

    const int lane = threadIdx.x & 63;
    const int wave = threadIdx.x >> 6;
    const int g    = lane >> 3;          // entry slot 0..7
    const int fl   = lane & 7;           // uint4 slot in token row

    for (;;) {
        int p0 = 0;
        if (lane == 0) p0 = (int)atomicAdd(counter, (unsigned)BATCH);
        p0 = __builtin_amdgcn_readfirstlane(p0);
        if (p0 >= N_PIXELS) break;
        const int pend = min(p0 + BATCH, N_PIXELS);

        for (int pixel = p0; pixel < pend; ++pixel) {
            const int start = indptr[pixel];
            const int end   = indptr[pixel + 1];

            float a0 = 0.f, a1 = 0.f, a2 = 0.f, a3 = 0.f;
            float a4 = 0.f, a5 = 0.f, a6 = 0.f, a7 = 0.f;

            for (int base = start; base < end; base += 64) {
                const int e = base + lane;
                int   idx   = 0;
                float scale = 0.0f;
                if (e < end) {
                    idx   = indices[e];
                    scale = cnts[e] * __expf(gamma[idx]);
                }
                int2 mt;
                mt.x = idx;
                mt.y = __float_as_int(scale);
                meta[wave][lane] = mt;   // wave-private; lgkmcnt orders it

                const int m = end - base;
                if (m >= 64) {
                    #pragma unroll 8
                    for (int j = 0; j < 8; ++j) {
                        const int2 mm = meta[wave][j * 8 + g];
                        const float s = __int_as_float(mm.y);
                        const uint4 t = tok_bf[mm.x * 8 + fl];
                        a0 = fmaf(__uint_as_float(t.x << 16), s, a0);
                        a1 = fmaf(__uint_as_float(t.x & 0xFFFF0000u), s, a1);
                        a2 = fmaf(__uint_as_float(t.y << 16), s, a2);
                        a3 = fmaf(__uint_as_float(t.y & 0xFFFF0000u), s, a3);
                        a4 = fmaf(__uint_as_float(t.z << 16), s, a4);
                        a5 = fmaf(__uint_as_float(t.z & 0xFFFF0000u), s, a5);
                        a6 = fmaf(__uint_as_float(t.w << 16), s, a6);
                        a7 = fmaf(__uint_as_float(t.w & 0xFFFF0000u), s, a7);
                    }
                } else {
                    const int niter = (m + 7) >> 3;   // invalid entries: scale=0
                    for (int j = 0; j < niter; ++j) {
                        const int2 mm = meta[wave][j * 8 + g];
                        const float s = __int_as_float(mm.y);
                        const uint4 t = tok_bf[mm.x * 8 + fl];
                        a0 = fmaf(__uint_as_float(t.x << 16), s, a0);
                        a1 = fmaf(__uint_as_float(t.x & 0xFFFF0000u), s, a1);
                        a2 = fmaf(__uint_as_float(t.y << 16), s, a2);
                        a3 = fmaf(__uint_as_float(t.y & 0xFFFF0000u), s, a3);
                        a4 = fmaf(__uint_as_float(t.z << 16), s, a4);
                        a5 = fmaf(__uint_as_float(t.z & 0xFFFF0000u), s, a5);
                        a6 = fmaf(__uint_as_float(t.w << 16), s, a6);
                        a7 = fmaf(__uint_as_float(t.w & 0xFFFF0000u), s, a7);
                    }
                }
            }

            // reduce across the 8 entry-groups (lane bits 3..5)
            #pragma unroll
            for (int mask = 8; mask <= 32; mask <<= 1) {
                a0 += __shfl_xor(a0, mask);
                a1 += __shfl_xor(a1, mask);
                a2 += __shfl_xor(a2, mask);
                a3 += __shfl_xor(a3, mask);
                a4 += __shfl_xor(a4, mask);
                a5 += __shfl_xor(a5, mask);
                a6 += __shfl_xor(a6, mask);
                a7 += __shfl_xor(a7, mask);
            }

            if (g == 0) {
                float4 lo = make_float4(a0, a1, a2, a3);
                float4 hi = make_float4(a4, a5, a6, a7);
                out4[pixel * 16 + fl * 2]     = lo;   // 8 lanes x 32 B
                out4[pixel * 16 + fl * 2 + 1] = hi;
            }
        }
    }
}

extern "C" void kernel_launch(void* const* d_in, const int* in_sizes, int n_in,
                              void* d_out, int out_size, void* d_ws, size_t ws_size,
                              hipStream_t stream) {
    const int*    indices = (const int*)d_in[0];
    const float*  cnts    = (const float*)d_in[1];
    const int*    indptr  = (const int*)d_in[2];
    const float*  gamma   = (const float*)d_in[3];
    const float4* tokens4 = (const float4*)d_in[4];
    float4*       out4    = (float4*)d_out;

    unsigned int* counter = (unsigned int*)d_ws;                 // 4 B at offset 0
    ushort4*      tok_bf  = (ushort4*)((char*)d_ws + 256);       // 3.84 MB table

    hipMemsetAsync(d_ws, 0, 4, stream);   // zero the work counter

    convert_tokens<<<1875, 256, 0, stream>>>(tokens4, tok_bf);

    sgstem_main<<<2048, WAVES_PER_BLOCK * 64, 0, stream>>>(
        indices, cnts, indptr, gamma, (const uint4*)tok_bf, out4, counter);
}

// Round 5
// 162.325 us; speedup vs baseline: 2.3247x; 2.3247x over previous
//
#include <hip/hip_runtime.h>
#include <hip/hip_bf16.h>

#define FDIM 64
#define N_PIXELS 65536
#define N_ENTRIES 4194304
#define N_GENES 30000
#define WAVES_PER_BLOCK 4
#define N_WAVES 8192
#define EPW (N_ENTRIES / N_WAVES)   // 512 entries per wave, exact

// ---------- kernel A: f32 tokens -> bf16 table in ws (RNE) ----------
__device__ __forceinline__ unsigned short f32_to_bf16_rne(float f) {
    unsigned int u = __float_as_uint(f);
    u = (u + 0x7FFFu + ((u >> 16) & 1u)) >> 16;
    return (unsigned short)u;
}

__global__ __launch_bounds__(256) void convert_tokens(
    const float4* __restrict__ tokens4,   // 480000 float4
    ushort4* __restrict__ tok_bf)         // 480000 ushort4 (bf16)
{
    const int i = blockIdx.x * blockDim.x + threadIdx.x;   // exactly 480000
    const float4 t = tokens4[i];
    ushort4 o;
    o.x = f32_to_bf16_rne(t.x);
    o.y = f32_to_bf16_rne(t.y);
    o.z = f32_to_bf16_rne(t.z);
    o.w = f32_to_bf16_rne(t.w);
    tok_bf[i] = o;
}

// ---------- kernel B: entry-partitioned gather-scatter ----------
// Wave w owns entries [w*EPW, (w+1)*EPW). Binary search locates the first
// pixel; walk pixels intersecting the range. Interior pixels: direct store.
// Boundary pixels (straddle a range edge): per-float atomicAdd onto the
// memset-zeroed output. Perfect static load balance (512 entries/wave).
__global__ __launch_bounds__(WAVES_PER_BLOCK * 64) void sgstem_main(
    const int* __restrict__ indices,
    const float* __restrict__ cnts,
    const int* __restrict__ indptr,
    const float* __restrict__ gamma,
    const uint4* __restrict__ tok_bf,     // (N_GENES, 8) uint4 rows
    float* __restrict__ out)              // (N_PIXELS, 64) f32, pre-zeroed
{
    __shared__ int2 meta[WAVES_PER_BLOCK][64];   // {idx, scale_bits}

    const int lane = threadIdx.x & 63;
    const int wave = threadIdx.x >> 6;
    const int g    = lane >> 3;          // entry slot 0..7
    const int fl   = lane & 7;           // uint4 slot in token row

    const int wid = __builtin_amdgcn_readfirstlane(
        blockIdx.x * WAVES_PER_BLOCK + wave);       // 0..8191, SGPR
    const int e0 = wid * EPW;
    const int e1 = e0 + EPW;

    // binary search: p = max{ i : indptr[i] <= e0 }  (indptr[0]=0 guarantees p>=0)
    int lo = 0, hi = N_PIXELS;
    while (lo < hi) {
        const int mid = (lo + hi + 1) >> 1;
        if (indptr[mid] <= e0) lo = mid; else hi = mid - 1;
    }
    int p = lo;

    while (p < N_PIXELS) {
        const int ps = indptr[p];
        if (ps >= e1) break;
        const int pe = indptr[p + 1];
        const int s = max(ps, e0);
        const int t = min(pe, e1);

        if (t > s) {
            float a0 = 0.f, a1 = 0.f, a2 = 0.f, a3 = 0.f;
            float a4 = 0.f, a5 = 0.f, a6 = 0.f, a7 = 0.f;

            for (int base = s; base < t; base += 64) {
                const int e = base + lane;
                int   idx   = 0;
                float scale = 0.0f;
                if (e < t) {
                    idx   = indices[e];
                    scale = cnts[e] * __expf(gamma[idx]);
                }
                int2 mt;
                mt.x = idx;
                mt.y = __float_as_int(scale);
                meta[wave][lane] = mt;   // wave-private; lgkmcnt orders it

                const int m = t - base;
                const int niter = (m >= 64) ? 8 : ((m + 7) >> 3);
                #pragma unroll 4
                for (int j = 0; j < niter; ++j) {
                    const int2 mm = meta[wave][j * 8 + g];
                    const float sc = __int_as_float(mm.y);
                    const uint4 tk = tok_bf[mm.x * 8 + fl];
                    a0 = fmaf(__uint_as_float(tk.x << 16), sc, a0);
                    a1 = fmaf(__uint_as_float(tk.x & 0xFFFF0000u), sc, a1);
                    a2 = fmaf(__uint_as_float(tk.y << 16), sc, a2);
                    a3 = fmaf(__uint_as_float(tk.y & 0xFFFF0000u), sc, a3);
                    a4 = fmaf(__uint_as_float(tk.z << 16), sc, a4);
                    a5 = fmaf(__uint_as_float(tk.z & 0xFFFF0000u), sc, a5);
                    a6 = fmaf(__uint_as_float(tk.w << 16), sc, a6);
                    a7 = fmaf(__uint_as_float(tk.w & 0xFFFF0000u), sc, a7);
                }
            }

            // reduce across the 8 entry-groups (lane bits 3..5)
            #pragma unroll
            for (int mask = 8; mask <= 32; mask <<= 1) {
                a0 += __shfl_xor(a0, mask);
                a1 += __shfl_xor(a1, mask);
                a2 += __shfl_xor(a2, mask);
                a3 += __shfl_xor(a3, mask);
                a4 += __shfl_xor(a4, mask);
                a5 += __shfl_xor(a5, mask);
                a6 += __shfl_xor(a6, mask);
                a7 += __shfl_xor(a7, mask);
            }

            if (g == 0) {
                const bool interior = (ps >= e0) && (pe <= e1);
                if (interior) {
                    float4* o4 = (float4*)(out + p * FDIM);
                    o4[fl * 2]     = make_float4(a0, a1, a2, a3);
                    o4[fl * 2 + 1] = make_float4(a4, a5, a6, a7);
                } else {
                    float* o = out + p * FDIM + fl * 8;
                    atomicAdd(o + 0, a0);
                    atomicAdd(o + 1, a1);
                    atomicAdd(o + 2, a2);
                    atomicAdd(o + 3, a3);
                    atomicAdd(o + 4, a4);
                    atomicAdd(o + 5, a5);
                    atomicAdd(o + 6, a6);
                    atomicAdd(o + 7, a7);
                }
            }
        }
        ++p;
    }
}

extern "C" void kernel_launch(void* const* d_in, const int* in_sizes, int n_in,
                              void* d_out, int out_size, void* d_ws, size_t ws_size,
                              hipStream_t stream) {
    const int*    indices = (const int*)d_in[0];
    const float*  cnts    = (const float*)d_in[1];
    const int*    indptr  = (const int*)d_in[2];
    const float*  gamma   = (const float*)d_in[3];
    const float4* tokens4 = (const float4*)d_in[4];
    float*        out     = (float*)d_out;

    ushort4* tok_bf = (ushort4*)d_ws;   // 3.84 MB bf16 token table

    // zero output (empty pixels + atomic accumulation base)
    hipMemsetAsync(d_out, 0, (size_t)N_PIXELS * FDIM * sizeof(float), stream);

    convert_tokens<<<1875, 256, 0, stream>>>(tokens4, tok_bf);

    sgstem_main<<<N_WAVES / WAVES_PER_BLOCK, WAVES_PER_BLOCK * 64, 0, stream>>>(
        indices, cnts, indptr, gamma, (const uint4*)tok_bf, out);
}

// Round 6
// 145.741 us; speedup vs baseline: 2.5892x; 1.1138x over previous
//
#include <hip/hip_runtime.h>
#include <hip/hip_bf16.h>

#define FDIM 64
#define N_PIXELS 65536
#define N_ENTRIES 4194304
#define N_GENES 30000
#define WAVES_PER_BLOCK 4
#define N_WAVES 8192
#define EPW 512   // entries per wave (exact: 8192*512 = 4194304)

// ---------- kernel A: tok_bf[g,:] = bf16( tokens[g,:] * exp(gamma[g]) ) ----------
__device__ __forceinline__ unsigned short f32_to_bf16_rne(float f) {
    unsigned int u = __float_as_uint(f);
    u = (u + 0x7FFFu + ((u >> 16) & 1u)) >> 16;
    return (unsigned short)u;
}

__global__ __launch_bounds__(256) void convert_tokens(
    const float4* __restrict__ tokens4,   // 480000 float4
    const float* __restrict__ gamma,
    ushort4* __restrict__ tok_bf)         // 480000 ushort4 (bf16)
{
    const int i = blockIdx.x * blockDim.x + threadIdx.x;   // exactly 480000
    const int g = i >> 4;                                   // gene row
    const float eg = __expf(gamma[g]);
    const float4 t = tokens4[i];
    ushort4 o;
    o.x = f32_to_bf16_rne(t.x * eg);
    o.y = f32_to_bf16_rne(t.y * eg);
    o.z = f32_to_bf16_rne(t.z * eg);
    o.w = f32_to_bf16_rne(t.w * eg);
    tok_bf[i] = o;
}

// ---------- kernel B: entry-partitioned, staged meta, depth-4 gather pipeline ----------
// Wave w owns entries [w*512, (w+1)*512). Phase A: stage all 512 {idx*8, cnt}
// to LDS (coalesced, independent). Phase B: walk pixels; per 32-entry batch
// issue 4 ds_read_b64 + 4 global_load_dwordx4 before consuming (depth-4 MLP).
// Interior pixels: direct store. Boundary pixels: per-float atomicAdd.
__global__ __launch_bounds__(WAVES_PER_BLOCK * 64, 8) void sgstem_main(
    const int* __restrict__ indices,
    const float* __restrict__ cnts,
    const int* __restrict__ indptr,
    const uint4* __restrict__ tok_bf,     // (N_GENES, 8) uint4 rows
    float* __restrict__ out)              // (N_PIXELS, 64) f32, pre-zeroed
{
    __shared__ int2 meta[WAVES_PER_BLOCK][EPW];   // {idx*8, cnt_bits} per entry

    const int lane = threadIdx.x & 63;
    const int wave = threadIdx.x >> 6;
    const int g    = lane >> 3;          // entry slot 0..7
    const int fl   = lane & 7;           // uint4 slot in token row

    const int wid = __builtin_amdgcn_readfirstlane(
        blockIdx.x * WAVES_PER_BLOCK + wave);       // SGPR -> scalar search
    const int e0 = wid * EPW;
    const int e1 = e0 + EPW;

    // ---- Phase A: stage all 512 entries (no masking needed, range in-bounds)
    #pragma unroll
    for (int c = 0; c < 8; ++c) {
        const int e = e0 + c * 64 + lane;
        const int   idx = indices[e];
        const float cnt = cnts[e];
        meta[wave][c * 64 + lane] = make_int2(idx * 8, __float_as_int(cnt));
    }

    // ---- binary search: p = max{ i : indptr[i] <= e0 }
    int lo = 0, hi = N_PIXELS;
    while (lo < hi) {
        const int mid = (lo + hi + 1) >> 1;
        if (indptr[mid] <= e0) lo = mid; else hi = mid - 1;
    }
    int p = lo;

    while (p < N_PIXELS) {
        const int ps = indptr[p];
        if (ps >= e1) break;
        const int pe = indptr[p + 1];
        const int s = max(ps, e0);
        const int t = min(pe, e1);

        if (t > s) {
            const int r0 = s - e0;
            const int r1 = t - e0;

            float a0 = 0.f, a1 = 0.f, a2 = 0.f, a3 = 0.f;
            float a4 = 0.f, a5 = 0.f, a6 = 0.f, a7 = 0.f;

            for (int rb = r0; rb < r1; rb += 32) {
                const int q0 = rb + g;
                const int q1 = q0 + 8;
                const int q2 = q0 + 16;
                const int q3 = q0 + 24;
                // LDS reads (clamped -> always a real entry of this wave)
                const int2 m0 = meta[wave][min(q0, EPW - 1)];
                const int2 m1 = meta[wave][min(q1, EPW - 1)];
                const int2 m2 = meta[wave][min(q2, EPW - 1)];
                const int2 m3 = meta[wave][min(q3, EPW - 1)];
                // 4 independent gathers in flight
                const uint4 t0 = tok_bf[m0.x + fl];
                const uint4 t1 = tok_bf[m1.x + fl];
                const uint4 t2 = tok_bf[m2.x + fl];
                const uint4 t3 = tok_bf[m3.x + fl];
                // predicated scales (invalid slot contributes 0)
                const float s0 = (q0 < r1) ? __int_as_float(m0.y) : 0.f;
                const float s1 = (q1 < r1) ? __int_as_float(m1.y) : 0.f;
                const float s2 = (q2 < r1) ? __int_as_float(m2.y) : 0.f;
                const float s3 = (q3 < r1) ? __int_as_float(m3.y) : 0.f;

                a0 = fmaf(__uint_as_float(t0.x << 16),        s0, a0);
                a1 = fmaf(__uint_as_float(t0.x & 0xFFFF0000u), s0, a1);
                a2 = fmaf(__uint_as_float(t0.y << 16),        s0, a2);
                a3 = fmaf(__uint_as_float(t0.y & 0xFFFF0000u), s0, a3);
                a4 = fmaf(__uint_as_float(t0.z << 16),        s0, a4);
                a5 = fmaf(__uint_as_float(t0.z & 0xFFFF0000u), s0, a5);
                a6 = fmaf(__uint_as_float(t0.w << 16),        s0, a6);
                a7 = fmaf(__uint_as_float(t0.w & 0xFFFF0000u), s0, a7);

                a0 = fmaf(__uint_as_float(t1.x << 16),        s1, a0);
                a1 = fmaf(__uint_as_float(t1.x & 0xFFFF0000u), s1, a1);
                a2 = fmaf(__uint_as_float(t1.y << 16),        s1, a2);
                a3 = fmaf(__uint_as_float(t1.y & 0xFFFF0000u), s1, a3);
                a4 = fmaf(__uint_as_float(t1.z << 16),        s1, a4);
                a5 = fmaf(__uint_as_float(t1.z & 0xFFFF0000u), s1, a5);
                a6 = fmaf(__uint_as_float(t1.w << 16),        s1, a6);
                a7 = fmaf(__uint_as_float(t1.w & 0xFFFF0000u), s1, a7);

                a0 = fmaf(__uint_as_float(t2.x << 16),        s2, a0);
                a1 = fmaf(__uint_as_float(t2.x & 0xFFFF0000u), s2, a1);
                a2 = fmaf(__uint_as_float(t2.y << 16),        s2, a2);
                a3 = fmaf(__uint_as_float(t2.y & 0xFFFF0000u), s2, a3);
                a4 = fmaf(__uint_as_float(t2.z << 16),        s2, a4);
                a5 = fmaf(__uint_as_float(t2.z & 0xFFFF0000u), s2, a5);
                a6 = fmaf(__uint_as_float(t2.w << 16),        s2, a6);
                a7 = fmaf(__uint_as_float(t2.w & 0xFFFF0000u), s2, a7);

                a0 = fmaf(__uint_as_float(t3.x << 16),        s3, a0);
                a1 = fmaf(__uint_as_float(t3.x & 0xFFFF0000u), s3, a1);
                a2 = fmaf(__uint_as_float(t3.y << 16),        s3, a2);
                a3 = fmaf(__uint_as_float(t3.y & 0xFFFF0000u), s3, a3);
                a4 = fmaf(__uint_as_float(t3.z << 16),        s3, a4);
                a5 = fmaf(__uint_as_float(t3.z & 0xFFFF0000u), s3, a5);
                a6 = fmaf(__uint_as_float(t3.w << 16),        s3, a6);
                a7 = fmaf(__uint_as_float(t3.w & 0xFFFF0000u), s3, a7);
            }

            // reduce across the 8 entry-groups (lane bits 3..5)
            #pragma unroll
            for (int mask = 8; mask <= 32; mask <<= 1) {
                a0 += __shfl_xor(a0, mask);
                a1 += __shfl_xor(a1, mask);
                a2 += __shfl_xor(a2, mask);
                a3 += __shfl_xor(a3, mask);
                a4 += __shfl_xor(a4, mask);
                a5 += __shfl_xor(a5, mask);
                a6 += __shfl_xor(a6, mask);
                a7 += __shfl_xor(a7, mask);
            }

            if (g == 0) {
                const bool interior = (ps >= e0) && (pe <= e1);
                if (interior) {
                    float4* o4 = (float4*)(out + p * FDIM);
                    o4[fl * 2]     = make_float4(a0, a1, a2, a3);
                    o4[fl * 2 + 1] = make_float4(a4, a5, a6, a7);
                } else {
                    float* o = out + p * FDIM + fl * 8;
                    atomicAdd(o + 0, a0);
                    atomicAdd(o + 1, a1);
                    atomicAdd(o + 2, a2);
                    atomicAdd(o + 3, a3);
                    atomicAdd(o + 4, a4);
                    atomicAdd(o + 5, a5);
                    atomicAdd(o + 6, a6);
                    atomicAdd(o + 7, a7);
                }
            }
        }
        ++p;
    }
}

extern "C" void kernel_launch(void* const* d_in, const int* in_sizes, int n_in,
                              void* d_out, int out_size, void* d_ws, size_t ws_size,
                              hipStream_t stream) {
    const int*    indices = (const int*)d_in[0];
    const float*  cnts    = (const float*)d_in[1];
    const int*    indptr  = (const int*)d_in[2];
    const float*  gamma   = (const float*)d_in[3];
    const float4* tokens4 = (const float4*)d_in[4];
    float*        out     = (float*)d_out;

    ushort4* tok_bf = (ushort4*)d_ws;   // 3.84 MB bf16 scaled token table

    hipMemsetAsync(d_out, 0, (size_t)N_PIXELS * FDIM * sizeof(float), stream);

    convert_tokens<<<1875, 256, 0, stream>>>(tokens4, gamma, tok_bf);

    sgstem_main<<<N_WAVES / WAVES_PER_BLOCK, WAVES_PER_BLOCK * 64, 0, stream>>>(
        indices, cnts, indptr, (const uint4*)tok_bf, out);
}